// Round 1
// baseline (435.970 us; speedup 1.0000x reference)
//
#include <hip/hip_runtime.h>

#define NS 32768
#define NE 4

typedef __attribute__((ext_vector_type(4))) float f32x4;
typedef __attribute__((ext_vector_type(8))) short bf16x8;

// fp32 -> bf16, round-to-nearest-even
__device__ __forceinline__ unsigned short f2bf(float f) {
    unsigned int u = __float_as_uint(f);
    u = (u + 0x7fffu + ((u >> 16) & 1u)) >> 16;
    return (unsigned short)u;
}

// Kernel 0: W[e][l][c][k] fp32  ->  Wt[e][l][k][c] bf16 (one block per (e,l))
__global__ void wt_transpose_kernel(const float* __restrict__ W,
                                    unsigned short* __restrict__ Wt) {
    const int el = blockIdx.x;  // e*4 + l
    const float* w = W + (size_t)el * 128 * 128;        // [c][k]
    unsigned short* wt = Wt + (size_t)el * 128 * 128;   // [k][c]
    for (int i = threadIdx.x; i < 128 * 128; i += 256) {
        int c = i & 127;
        int k = i >> 7;
        wt[k * 128 + c] = f2bf(w[c * 128 + k]);
    }
}

// Kernel 1: build per-expert index lists (order within a list is irrelevant)
__global__ void gather_kernel(const float* __restrict__ y,
                              int* __restrict__ cnt, int* __restrict__ idx) {
    int n = blockIdx.x * 256 + threadIdx.x;
    if (n >= NS) return;
    const float* yr = y + n * 4;
    int e = 0;
    if (yr[1] > 0.5f) e = 1;
    else if (yr[2] > 0.5f) e = 2;
    else if (yr[3] > 0.5f) e = 3;
    int pos = atomicAdd(&cnt[e], 1);
    idx[e * NS + pos] = n;
}

// Kernel 2 (per l): gathered-row GEMM.
// MFMA orientation: D = A·B with A = Wt tile (16 kcols x 32 c),
// B = x^T tile (32 c x 16 gathered rows). All per-lane loads contiguous.
template <int L, int M>
__global__ __launch_bounds__(256) void gemm_kernel(
    const float* __restrict__ x, const unsigned short* __restrict__ Wt,
    const int* __restrict__ cnt, const int* __restrict__ idx,
    float* __restrict__ out) {
    const int e = blockIdx.y;
    const int rows_total = cnt[e] * M;
    const int R0 = blockIdx.x * 64;           // 4 waves x 16 rows
    if (R0 >= rows_total) return;

    const int wave = threadIdx.x >> 6;
    const int lane = threadIdx.x & 63;
    const int half = lane >> 4;               // 0..3
    const int li = lane & 15;

    int g = R0 + wave * 16 + li;              // row within (e,L) sub-problem
    const bool valid = g < rows_total;
    int gc = valid ? g : rows_total - 1;      // clamp for safe loads
    int pos = gc / M;                         // M is compile-time -> magic mul
    int j = gc - pos * M;
    int n = idx[e * NS + pos];
    int row = n * 16 + L * L + j;
    const float* xrow = x + (size_t)row * 128;
    float* orow = out + (size_t)row * 128;
    const unsigned short* wb = Wt + (size_t)(e * 4 + L) * 128 * 128;  // [k][c]

    f32x4 acc[8];
#pragma unroll
    for (int t = 0; t < 8; ++t) acc[t] = (f32x4){0.f, 0.f, 0.f, 0.f};

    const int c0 = half * 8;
#pragma unroll
    for (int kk = 0; kk < 128; kk += 32) {
        // B fragment: lane holds col j = li (its gathered row), k = half*8 + r
        f32x4 b0 = *(const f32x4*)(xrow + kk + c0);
        f32x4 b1 = *(const f32x4*)(xrow + kk + c0 + 4);
        bf16x8 bfrag;
        bfrag[0] = (short)f2bf(b0.x);
        bfrag[1] = (short)f2bf(b0.y);
        bfrag[2] = (short)f2bf(b0.z);
        bfrag[3] = (short)f2bf(b0.w);
        bfrag[4] = (short)f2bf(b1.x);
        bfrag[5] = (short)f2bf(b1.y);
        bfrag[6] = (short)f2bf(b1.z);
        bfrag[7] = (short)f2bf(b1.w);
#pragma unroll
        for (int t = 0; t < 8; ++t) {
            // A fragment: lane holds row i = li -> kcol = t*16+li, k = half*8 + r
            bf16x8 afrag =
                *(const bf16x8*)(wb + (t * 16 + li) * 128 + kk + c0);
            acc[t] = __builtin_amdgcn_mfma_f32_16x16x32_bf16(afrag, bfrag,
                                                             acc[t], 0, 0, 0);
        }
    }

    if (valid) {
        const float pw = 0.088388347648318447f;  // 1/sqrt(128)
#pragma unroll
        for (int t = 0; t < 8; ++t) {
            // D: lane holds col = li (its row), M-rows = half*4 + reg -> kcol
            f32x4 v = acc[t] * pw;
            *(f32x4*)(orow + t * 16 + half * 4) = v;
        }
    }
}

extern "C" void kernel_launch(void* const* d_in, const int* in_sizes, int n_in,
                              void* d_out, int out_size, void* d_ws,
                              size_t ws_size, hipStream_t stream) {
    const float* x = (const float*)d_in[0];
    const float* y = (const float*)d_in[1];
    const float* W = (const float*)d_in[2];
    float* out = (float*)d_out;

    char* ws = (char*)d_ws;
    int* cnt = (int*)ws;                                  // 16 B
    int* idx = (int*)(ws + 64);                           // 512 KB
    unsigned short* Wt = (unsigned short*)(ws + 64 + NE * NS * 4);  // 512 KB

    hipMemsetAsync(cnt, 0, NE * sizeof(int), stream);
    wt_transpose_kernel<<<16, 256, 0, stream>>>(W, Wt);
    gather_kernel<<<NS / 256, 256, 0, stream>>>(y, cnt, idx);

    gemm_kernel<0, 1><<<dim3((NS * 1 + 63) / 64, NE), 256, 0, stream>>>(
        x, Wt, cnt, idx, out);
    gemm_kernel<1, 3><<<dim3((NS * 3 + 63) / 64, NE), 256, 0, stream>>>(
        x, Wt, cnt, idx, out);
    gemm_kernel<2, 5><<<dim3((NS * 5 + 63) / 64, NE), 256, 0, stream>>>(
        x, Wt, cnt, idx, out);
    gemm_kernel<3, 7><<<dim3((NS * 7 + 63) / 64, NE), 256, 0, stream>>>(
        x, Wt, cnt, idx, out);
}

// Round 2
// 279.130 us; speedup vs baseline: 1.5619x; 1.5619x over previous
//
#include <hip/hip_runtime.h>

#define NS 32768
#define NE 4

typedef __attribute__((ext_vector_type(4))) float f32x4;
typedef __attribute__((ext_vector_type(8))) short bf16x8;

// fp32 -> bf16, round-to-nearest-even
__device__ __forceinline__ unsigned short f2bf(float f) {
    unsigned int u = __float_as_uint(f);
    u = (u + 0x7fffu + ((u >> 16) & 1u)) >> 16;
    return (unsigned short)u;
}

// Kernel 0: W[e][l][c][k] fp32  ->  Wt[e][l][k][c] bf16 (one block per (e,l))
__global__ void wt_transpose_kernel(const float* __restrict__ W,
                                    unsigned short* __restrict__ Wt) {
    const int el = blockIdx.x;  // e*4 + l
    const float* w = W + (size_t)el * 128 * 128;        // [c][k]
    unsigned short* wt = Wt + (size_t)el * 128 * 128;   // [k][c]
    for (int i = threadIdx.x; i < 128 * 128; i += 256) {
        int c = i & 127;
        int k = i >> 7;
        wt[k * 128 + c] = f2bf(w[c * 128 + k]);
    }
}

// Kernel 1: per-expert index lists, wave-aggregated atomics (1 atomic per
// wave per expert instead of 1 per thread -> no L2 atomic contention).
__global__ void gather_kernel(const float* __restrict__ y,
                              int* __restrict__ cnt, int* __restrict__ idx) {
    int n = blockIdx.x * 256 + threadIdx.x;
    const float4 yr = ((const float4*)y)[n];
    int e = 0;
    if (yr.y > 0.5f) e = 1;
    else if (yr.z > 0.5f) e = 2;
    else if (yr.w > 0.5f) e = 3;

    const int lane = threadIdx.x & 63;
    int pos = 0;
#pragma unroll
    for (int ee = 0; ee < NE; ++ee) {
        unsigned long long m = __ballot(e == ee);
        if (m == 0) continue;  // wave-uniform (ballot result is uniform)
        int leader = __builtin_ctzll(m);
        int base = 0;
        if (lane == leader) base = atomicAdd(&cnt[ee], __popcll(m));
        base = __shfl(base, leader);
        if (e == ee) pos = base + __popcll(m & ((1ull << lane) - 1ull));
    }
    idx[e * NS + pos] = n;
}

// Gathered-row GEMM body (one <L,M> instantiation per l).
// MFMA orientation: D = A·B with A = Wt tile (16 kcols x 32 c),
// B = x^T tile (32 c x 16 gathered rows). All per-lane loads contiguous.
template <int L, int M>
__device__ __forceinline__ void gemm_body(
    int tile, int e, const float* __restrict__ x,
    const unsigned short* __restrict__ Wt, const int* __restrict__ cnt,
    const int* __restrict__ idx, float* __restrict__ out) {
    const int rows_total = cnt[e] * M;
    const int R0 = tile * 64;                 // 4 waves x 16 rows
    if (R0 >= rows_total) return;

    const int wave = threadIdx.x >> 6;
    const int lane = threadIdx.x & 63;
    const int half = lane >> 4;               // 0..3
    const int li = lane & 15;

    int g = R0 + wave * 16 + li;              // row within (e,L) sub-problem
    const bool valid = g < rows_total;
    int gc = valid ? g : rows_total - 1;      // clamp for safe loads
    int pos = gc / M;                         // M compile-time -> magic mul
    int j = gc - pos * M;
    int n = idx[e * NS + pos];
    int row = n * 16 + L * L + j;
    const float* xrow = x + (size_t)row * 128;
    float* orow = out + (size_t)row * 128;
    const unsigned short* wb = Wt + (size_t)(e * 4 + L) * 128 * 128;  // [k][c]

    f32x4 acc[8];
#pragma unroll
    for (int t = 0; t < 8; ++t) acc[t] = (f32x4){0.f, 0.f, 0.f, 0.f};

    const int c0 = half * 8;
#pragma unroll
    for (int kk = 0; kk < 128; kk += 32) {
        // B fragment: lane holds col j = li (its gathered row), k = c0 + r
        f32x4 b0 = *(const f32x4*)(xrow + kk + c0);
        f32x4 b1 = *(const f32x4*)(xrow + kk + c0 + 4);
        bf16x8 bfrag;
        bfrag[0] = (short)f2bf(b0.x);
        bfrag[1] = (short)f2bf(b0.y);
        bfrag[2] = (short)f2bf(b0.z);
        bfrag[3] = (short)f2bf(b0.w);
        bfrag[4] = (short)f2bf(b1.x);
        bfrag[5] = (short)f2bf(b1.y);
        bfrag[6] = (short)f2bf(b1.z);
        bfrag[7] = (short)f2bf(b1.w);
#pragma unroll
        for (int t = 0; t < 8; ++t) {
            // A fragment: lane holds row i = li -> kcol = t*16+li, k = c0 + r
            bf16x8 afrag =
                *(const bf16x8*)(wb + (t * 16 + li) * 128 + kk + c0);
            acc[t] = __builtin_amdgcn_mfma_f32_16x16x32_bf16(afrag, bfrag,
                                                             acc[t], 0, 0, 0);
        }
    }

    if (valid) {
        const float pw = 0.088388347648318447f;  // 1/sqrt(128)
#pragma unroll
        for (int t = 0; t < 8; ++t) {
            f32x4 v = acc[t] * pw;
            *(f32x4*)(orow + t * 16 + half * 4) = v;
        }
    }
}

// Fused over all 4 l-values: blockIdx.x range picks the <L,M> instantiation.
// Worst-case tiles per l: 512*M  ->  offsets 0, 512, 2048, 4608; total 8192.
__global__ __launch_bounds__(256) void gemm_all_kernel(
    const float* __restrict__ x, const unsigned short* __restrict__ Wt,
    const int* __restrict__ cnt, const int* __restrict__ idx,
    float* __restrict__ out) {
    const int bx = blockIdx.x;
    const int e = blockIdx.y;
    if (bx < 512)       gemm_body<0, 1>(bx,        e, x, Wt, cnt, idx, out);
    else if (bx < 2048) gemm_body<1, 3>(bx - 512,  e, x, Wt, cnt, idx, out);
    else if (bx < 4608) gemm_body<2, 5>(bx - 2048, e, x, Wt, cnt, idx, out);
    else                gemm_body<3, 7>(bx - 4608, e, x, Wt, cnt, idx, out);
}

extern "C" void kernel_launch(void* const* d_in, const int* in_sizes, int n_in,
                              void* d_out, int out_size, void* d_ws,
                              size_t ws_size, hipStream_t stream) {
    const float* x = (const float*)d_in[0];
    const float* y = (const float*)d_in[1];
    const float* W = (const float*)d_in[2];
    float* out = (float*)d_out;

    char* ws = (char*)d_ws;
    int* cnt = (int*)ws;                                  // 16 B
    int* idx = (int*)(ws + 64);                           // 512 KB
    unsigned short* Wt = (unsigned short*)(ws + 64 + NE * NS * 4);  // 512 KB

    hipMemsetAsync(cnt, 0, NE * sizeof(int), stream);
    wt_transpose_kernel<<<16, 256, 0, stream>>>(W, Wt);
    gather_kernel<<<NS / 256, 256, 0, stream>>>(y, cnt, idx);
    gemm_all_kernel<<<dim3(8192, NE), 256, 0, stream>>>(x, Wt, cnt, idx, out);
}

// Round 3
// 269.100 us; speedup vs baseline: 1.6201x; 1.0373x over previous
//
#include <hip/hip_runtime.h>

#define NS 32768
#define NE 4

typedef __attribute__((ext_vector_type(4))) float f32x4;
typedef __attribute__((ext_vector_type(8))) short bf16x8;

// fp32 -> bf16, round-to-nearest-even
__device__ __forceinline__ unsigned short f2bf(float f) {
    unsigned int u = __float_as_uint(f);
    u = (u + 0x7fffu + ((u >> 16) & 1u)) >> 16;
    return (unsigned short)u;
}

// Prep: blocks 0..15 transpose W[e][l][c][k] -> Wt[e][l][k][c] bf16;
// blocks 16..143 build per-expert index lists (wave-aggregated atomics).
__global__ void prep_kernel(const float* __restrict__ W,
                            unsigned short* __restrict__ Wt,
                            const float* __restrict__ y,
                            int* __restrict__ cnt, int* __restrict__ idx) {
    const int b = blockIdx.x;
    if (b < 16) {
        const float* w = W + (size_t)b * 16384;         // [c][k]
        unsigned short* wt = Wt + (size_t)b * 16384;    // [k][c]
        for (int i = threadIdx.x; i < 16384; i += 256) {
            int c = i & 127, k = i >> 7;
            wt[k * 128 + c] = f2bf(w[c * 128 + k]);
        }
        return;
    }
    int n = (b - 16) * 256 + threadIdx.x;
    const float4 yr = ((const float4*)y)[n];
    int e = 0;
    if (yr.y > 0.5f) e = 1;
    else if (yr.z > 0.5f) e = 2;
    else if (yr.w > 0.5f) e = 3;
    const int lane = threadIdx.x & 63;
    int pos = 0;
#pragma unroll
    for (int ee = 0; ee < NE; ++ee) {
        unsigned long long m = __ballot(e == ee);
        if (m == 0) continue;
        int leader = __builtin_ctzll(m);
        int base = 0;
        if (lane == leader) base = atomicAdd(&cnt[ee], __popcll(m));
        base = __shfl(base, leader);
        if (e == ee) pos = base + __popcll(m & ((1ull << lane) - 1ull));
    }
    idx[e * NS + pos] = n;
}

// One 64-row tile of the (e,L) gathered GEMM.
// MFMA: D = A·B, A = Wt tile (16 kcols x 32 c), B = x^T tile (32 c x 16 rows).
// ALL 8 x-loads issued up-front -> single HBM latency exposure per tile.
template <int L, int M>
__device__ __forceinline__ void gemm_tile(
    int tile, int e, int cn, const float* __restrict__ x,
    const unsigned short* __restrict__ Wt, const int* __restrict__ idx,
    float* __restrict__ out) {
    const int rows_total = cn * M;
    const int lane = threadIdx.x & 63;
    const int wave = threadIdx.x >> 6;
    const int half = lane >> 4;   // 0..3
    const int li = lane & 15;

    int g = tile * 64 + wave * 16 + li;
    const bool valid = g < rows_total;
    int gc = valid ? g : rows_total - 1;      // clamp for safe loads
    int pos = gc / M;                          // compile-time M -> magic mul
    int j = gc - pos * M;
    int n = idx[e * NS + pos];
    int row = n * 16 + L * L + j;
    const float* xrow = x + (size_t)row * 128;
    const unsigned short* wb = Wt + (size_t)(e * 4 + L) * 16384;  // [k][c]
    const int c0 = half * 8;

    // Issue all global x loads back-to-back (8 in flight).
    f32x4 bv[8];
#pragma unroll
    for (int i = 0; i < 4; ++i) {
        bv[2 * i]     = *(const f32x4*)(xrow + i * 32 + c0);
        bv[2 * i + 1] = *(const f32x4*)(xrow + i * 32 + c0 + 4);
    }
    bf16x8 bfrag[4];
#pragma unroll
    for (int i = 0; i < 4; ++i) {
        bfrag[i][0] = (short)f2bf(bv[2 * i].x);
        bfrag[i][1] = (short)f2bf(bv[2 * i].y);
        bfrag[i][2] = (short)f2bf(bv[2 * i].z);
        bfrag[i][3] = (short)f2bf(bv[2 * i].w);
        bfrag[i][4] = (short)f2bf(bv[2 * i + 1].x);
        bfrag[i][5] = (short)f2bf(bv[2 * i + 1].y);
        bfrag[i][6] = (short)f2bf(bv[2 * i + 1].z);
        bfrag[i][7] = (short)f2bf(bv[2 * i + 1].w);
    }

    f32x4 acc[8];
#pragma unroll
    for (int t = 0; t < 8; ++t) acc[t] = (f32x4){0.f, 0.f, 0.f, 0.f};

#pragma unroll
    for (int kk = 0; kk < 4; ++kk) {
#pragma unroll
        for (int t = 0; t < 8; ++t) {
            // weight panel: 32 KB, L1-resident, shared by the whole block
            bf16x8 afrag =
                *(const bf16x8*)(wb + (t * 16 + li) * 128 + kk * 32 + c0);
            acc[t] = __builtin_amdgcn_mfma_f32_16x16x32_bf16(afrag, bfrag[kk],
                                                             acc[t], 0, 0, 0);
        }
    }

    if (valid) {
        float* orow = out + (size_t)row * 128;
        const float pw = 0.088388347648318447f;  // 1/sqrt(128)
#pragma unroll
        for (int t = 0; t < 8; ++t) {
            f32x4 v = acc[t] * pw;
            *(f32x4*)(orow + t * 16 + half * 4) = v;
        }
    }
}

// Persistent: grid-stride over the exact (device-computed) tile count.
__global__ __launch_bounds__(256, 4) void gemm_persist(
    const float* __restrict__ x, const unsigned short* __restrict__ Wt,
    const int* __restrict__ cnt, const int* __restrict__ idx,
    float* __restrict__ out) {
    const int ce0 = cnt[0], ce1 = cnt[1], ce2 = cnt[2], ce3 = cnt[3];

    int tc[16];  // all indexing compile-time after unroll -> registers
#pragma unroll
    for (int ee = 0; ee < 4; ++ee) {
        int c = (ee == 0) ? ce0 : (ee == 1) ? ce1 : (ee == 2) ? ce2 : ce3;
#pragma unroll
        for (int l = 0; l < 4; ++l) tc[ee * 4 + l] = (c * (2 * l + 1) + 63) >> 6;
    }
    int total = 0;
#pragma unroll
    for (int i = 0; i < 16; ++i) total += tc[i];

    for (int t = blockIdx.x; t < total; t += gridDim.x) {
        int rem = t;
        int sel = -1;
#pragma unroll
        for (int i = 0; i < 16; ++i) {
            if (sel < 0) {
                if (rem < tc[i]) sel = i;
                else rem -= tc[i];
            }
        }
        const int e = sel >> 2, L = sel & 3;
        const int cn = (e == 0) ? ce0 : (e == 1) ? ce1 : (e == 2) ? ce2 : ce3;
        switch (L) {
            case 0: gemm_tile<0, 1>(rem, e, cn, x, Wt, idx, out); break;
            case 1: gemm_tile<1, 3>(rem, e, cn, x, Wt, idx, out); break;
            case 2: gemm_tile<2, 5>(rem, e, cn, x, Wt, idx, out); break;
            case 3: gemm_tile<3, 7>(rem, e, cn, x, Wt, idx, out); break;
        }
    }
}

extern "C" void kernel_launch(void* const* d_in, const int* in_sizes, int n_in,
                              void* d_out, int out_size, void* d_ws,
                              size_t ws_size, hipStream_t stream) {
    const float* x = (const float*)d_in[0];
    const float* y = (const float*)d_in[1];
    const float* W = (const float*)d_in[2];
    float* out = (float*)d_out;

    char* ws = (char*)d_ws;
    int* cnt = (int*)ws;                                            // 16 B
    int* idx = (int*)(ws + 64);                                     // 512 KB
    unsigned short* Wt = (unsigned short*)(ws + 64 + NE * NS * 4);  // 512 KB

    hipMemsetAsync(cnt, 0, NE * sizeof(int), stream);
    prep_kernel<<<16 + NS / 256, 256, 0, stream>>>(W, Wt, y, cnt, idx);
    gemm_persist<<<2048, 256, 0, stream>>>(x, Wt, cnt, idx, out);
}

// Round 4
// 158.227 us; speedup vs baseline: 2.7553x; 1.7007x over previous
//
#include <hip/hip_runtime.h>

#define NS 32768
#define NE 4

typedef __attribute__((ext_vector_type(4))) float f32x4;
typedef __attribute__((ext_vector_type(8))) short bf16x8;

// fp32 -> bf16, round-to-nearest-even
__device__ __forceinline__ unsigned short f2bf(float f) {
    unsigned int u = __float_as_uint(f);
    u = (u + 0x7fffu + ((u >> 16) & 1u)) >> 16;
    return (unsigned short)u;
}

// Prep: blocks 0..15 transpose W[e][l][c][k] -> Wt[e][l][k][c] bf16;
// blocks 16..143 build per-expert index lists (wave-aggregated atomics).
__global__ void prep_kernel(const float* __restrict__ W,
                            unsigned short* __restrict__ Wt,
                            const float* __restrict__ y,
                            int* __restrict__ cnt, int* __restrict__ idx) {
    const int b = blockIdx.x;
    if (b < 16) {
        const float* w = W + (size_t)b * 16384;         // [c][k]
        unsigned short* wt = Wt + (size_t)b * 16384;    // [k][c]
        for (int i = threadIdx.x; i < 16384; i += 256) {
            int c = i & 127, k = i >> 7;
            wt[k * 128 + c] = f2bf(w[c * 128 + k]);
        }
        return;
    }
    int n = (b - 16) * 256 + threadIdx.x;
    const float4 yr = ((const float4*)y)[n];
    int e = 0;
    if (yr.y > 0.5f) e = 1;
    else if (yr.z > 0.5f) e = 2;
    else if (yr.w > 0.5f) e = 3;
    const int lane = threadIdx.x & 63;
    int pos = 0;
#pragma unroll
    for (int ee = 0; ee < NE; ++ee) {
        unsigned long long m = __ballot(e == ee);
        if (m == 0) continue;
        int leader = __builtin_ctzll(m);
        int base = 0;
        if (lane == leader) base = atomicAdd(&cnt[ee], __popcll(m));
        base = __shfl(base, leader);
        if (e == ee) pos = base + __popcll(m & ((1ull << lane) - 1ull));
    }
    idx[e * NS + pos] = n;
}

// LDS layout: [0, 32768)  weight panel bf16 [k=128][c=128], XOR-swizzled
//             [32768, 49152) per-wave x tiles bf16 [16 rows][c=128], swizzled
// Swizzle: byte ^= ((row & 7) << 4)  -> conflict-free ds_read_b128 fragments.
template <int L, int M>
__device__ __forceinline__ void gemm_body(
    int e, int bi, int nb, unsigned char* lds, const float* __restrict__ x,
    const unsigned short* __restrict__ Wt, const int* __restrict__ cnt,
    const int* __restrict__ idx, float* __restrict__ out) {
    const int rows_total = cnt[e] * M;

    // Stage weight panel once per block; contiguous 4 KB per instruction.
    {
        const unsigned char* wp =
            (const unsigned char*)(Wt + (size_t)(e * 4 + L) * 16384);
        const int t = threadIdx.x;
#pragma unroll
        for (int q = 0; q < 8; ++q) {
            int o = q * 4096 + t * 16;
            uint4 v = *(const uint4*)(wp + o);
            int so = o ^ (((o >> 8) & 7) << 4);   // o>>8 = k row (256 B rows)
            *(uint4*)(lds + so) = v;
        }
    }
    __syncthreads();

    const int lane = threadIdx.x & 63;
    const int wv = threadIdx.x >> 6;
    const int li = lane & 15;
    const int half = lane >> 4;   // 0..3
    const int i5 = lane >> 5;     // 0..1
    const int c32 = lane & 31;
    unsigned char* xl = lds + 32768 + wv * 4096;  // this wave's private x tile

    for (int tile = bi; tile * 64 < rows_total; tile += nb) {
        int g = tile * 64 + wv * 16 + li;
        bool valid = g < rows_total;
        int gc = valid ? g : rows_total - 1;      // clamp for safe loads
        int pos = gc / M;                         // compile-time M
        int jj = gc - pos * M;
        int xrow = idx[e * NS + pos] * 16 + L * L + jj;

        // Stage 16 rows: instr q covers rows 2q,2q+1 fully contiguous.
        f32x4 bv[8];
#pragma unroll
        for (int q = 0; q < 8; ++q) {
            int tr = 2 * q + i5;
            int nr = __shfl(xrow, tr);            // lane tr holds row tr's base
            bv[q] = *(const f32x4*)(x + (size_t)nr * 128 + c32 * 4);
        }
#pragma unroll
        for (int q = 0; q < 8; ++q) {
            int tr = 2 * q + i5;
            unsigned int p0 = (unsigned int)f2bf(bv[q].x) |
                              ((unsigned int)f2bf(bv[q].y) << 16);
            unsigned int p1 = (unsigned int)f2bf(bv[q].z) |
                              ((unsigned int)f2bf(bv[q].w) << 16);
            uint2 pk; pk.x = p0; pk.y = p1;
            int off = (c32 * 8) ^ ((tr & 7) << 4);
            *(uint2*)(xl + tr * 256 + off) = pk;
        }

        f32x4 acc[8];
#pragma unroll
        for (int t = 0; t < 8; ++t) acc[t] = (f32x4){0.f, 0.f, 0.f, 0.f};

#pragma unroll
        for (int kk = 0; kk < 4; ++kk) {
            int co = (kk * 64 + half * 16) ^ ((li & 7) << 4);
            bf16x8 bfrag = *(const bf16x8*)(xl + li * 256 + co);
#pragma unroll
            for (int t = 0; t < 8; ++t) {
                bf16x8 afrag = *(const bf16x8*)(lds + (t * 16 + li) * 256 + co);
                acc[t] = __builtin_amdgcn_mfma_f32_16x16x32_bf16(afrag, bfrag,
                                                                 acc[t], 0, 0, 0);
            }
        }

        if (valid) {
            float* orow = out + (size_t)xrow * 128;
            const float pw = 0.088388347648318447f;  // 1/sqrt(128)
#pragma unroll
            for (int t = 0; t < 8; ++t) {
                *(f32x4*)(orow + t * 16 + half * 4) = acc[t] * pw;
            }
        }
    }
}

// Static (e,l) partition: per e (512 blocks): l0:32, l1:96, l2:160, l3:224
// (proportional to 2l+1 -> ~4 tiles per block regardless of l).
__global__ __launch_bounds__(256, 3) void gemm_main(
    const float* __restrict__ x, const unsigned short* __restrict__ Wt,
    const int* __restrict__ cnt, const int* __restrict__ idx,
    float* __restrict__ out) {
    __shared__ __align__(16) unsigned char lds[49152];
    const int b = blockIdx.x;
    const int e = b >> 9;
    const int r = b & 511;
    if (r < 32)       gemm_body<0, 1>(e, r,       32,  lds, x, Wt, cnt, idx, out);
    else if (r < 128) gemm_body<1, 3>(e, r - 32,  96,  lds, x, Wt, cnt, idx, out);
    else if (r < 288) gemm_body<2, 5>(e, r - 128, 160, lds, x, Wt, cnt, idx, out);
    else              gemm_body<3, 7>(e, r - 288, 224, lds, x, Wt, cnt, idx, out);
}

extern "C" void kernel_launch(void* const* d_in, const int* in_sizes, int n_in,
                              void* d_out, int out_size, void* d_ws,
                              size_t ws_size, hipStream_t stream) {
    const float* x = (const float*)d_in[0];
    const float* y = (const float*)d_in[1];
    const float* W = (const float*)d_in[2];
    float* out = (float*)d_out;

    char* ws = (char*)d_ws;
    int* cnt = (int*)ws;                                            // 16 B
    int* idx = (int*)(ws + 64);                                     // 512 KB
    unsigned short* Wt = (unsigned short*)(ws + 64 + NE * NS * 4);  // 512 KB

    hipMemsetAsync(cnt, 0, NE * sizeof(int), stream);
    prep_kernel<<<16 + NS / 256, 256, 0, stream>>>(W, Wt, y, cnt, idx);
    gemm_main<<<2048, 256, 0, stream>>>(x, Wt, cnt, idx, out);
}